// Round 10
// baseline (950.711 us; speedup 1.0000x reference)
//
#include <hip/hip_runtime.h>
#include <hip/hip_bf16.h>
#include <stdint.h>

#define B_  4
#define S_  2048
#define BS_ (B_ * S_)   // 8192 tokens
#define D_  1024
#define O_  1024
#define H_  8

#define BM 128
#define BN 128
#define BK 64
#define KT 16           // D_/BK

typedef unsigned short u16;
typedef __attribute__((ext_vector_type(8))) short     short8;
typedef __attribute__((ext_vector_type(8))) unsigned short ushort8v;
typedef __attribute__((ext_vector_type(4))) float     f32x4;

__device__ __forceinline__ u16 f2bf(float f) {
  unsigned u = __float_as_uint(f);
  unsigned r = (u + 0x7fffu + ((u >> 16) & 1u)) >> 16;
  return (u16)r;
}

#define GLOAD16(gp, lp)                                                        \
  __builtin_amdgcn_global_load_lds(                                            \
      (const __attribute__((address_space(1))) void*)(gp),                     \
      (__attribute__((address_space(3))) void*)(lp), 16, 0, 0)

// ---------------------------------------------------------------------------
// Kernel 1: gates (f32, one wave per token) + x -> bf16 conversion
// ---------------------------------------------------------------------------
__global__ __launch_bounds__(256) void gate_conv_kernel(
    const float* __restrict__ x, const float* __restrict__ gate_w,
    const float* __restrict__ gate_b, u16* __restrict__ x_bf,
    float* __restrict__ g_out) {
  const int wave  = threadIdx.x >> 6;
  const int lane  = threadIdx.x & 63;
  const int token = blockIdx.x * 4 + wave;
  const float* xr = x + (size_t)token * D_;
  const int d0 = lane * 16;

  float4 xv[4];
#pragma unroll
  for (int i = 0; i < 4; ++i) xv[i] = *(const float4*)(xr + d0 + i * 4);

  ushort8v lo, hi;
#pragma unroll
  for (int i = 0; i < 2; ++i) {
    lo[i * 4 + 0] = f2bf(xv[i].x); lo[i * 4 + 1] = f2bf(xv[i].y);
    lo[i * 4 + 2] = f2bf(xv[i].z); lo[i * 4 + 3] = f2bf(xv[i].w);
    hi[i * 4 + 0] = f2bf(xv[2 + i].x); hi[i * 4 + 1] = f2bf(xv[2 + i].y);
    hi[i * 4 + 2] = f2bf(xv[2 + i].z); hi[i * 4 + 3] = f2bf(xv[2 + i].w);
  }
  *(ushort8v*)(x_bf + (size_t)token * D_ + d0) = lo;
  *(ushort8v*)(x_bf + (size_t)token * D_ + d0 + 8) = hi;

  float s[H_];
#pragma unroll
  for (int h = 0; h < H_; ++h) {
    const float* gw = gate_w + h * D_ + d0;
    float a = 0.f;
#pragma unroll
    for (int i = 0; i < 4; ++i) {
      float4 w = *(const float4*)(gw + i * 4);
      a += xv[i].x * w.x + xv[i].y * w.y + xv[i].z * w.z + xv[i].w * w.w;
    }
    s[h] = a;
  }
#pragma unroll
  for (int h = 0; h < H_; ++h) {
#pragma unroll
    for (int off = 32; off > 0; off >>= 1) s[h] += __shfl_xor(s[h], off);
    s[h] += gate_b[h];
  }
  float m = s[0];
#pragma unroll
  for (int h = 1; h < H_; ++h) m = fmaxf(m, s[h]);
  float sum = 0.f;
#pragma unroll
  for (int h = 0; h < H_; ++h) { s[h] = expf(s[h] - m); sum += s[h]; }
  const float inv = 1.0f / sum;
#pragma unroll
  for (int h = 0; h < H_; ++h) s[h] *= inv;

  if (lane == 0) {
    float4 g0 = make_float4(s[0], s[1], s[2], s[3]);
    float4 g1 = make_float4(s[4], s[5], s[6], s[7]);
    *(float4*)(g_out + (size_t)token * H_)     = g0;
    *(float4*)(g_out + (size_t)token * H_ + 4) = g1;
  }
}

// ---------------------------------------------------------------------------
// Kernel 2: expert_w f32 -> bf16
// ---------------------------------------------------------------------------
__global__ __launch_bounds__(256) void convw_kernel(
    const float* __restrict__ w, u16* __restrict__ wb) {
  size_t i = ((size_t)blockIdx.x * 256 + threadIdx.x) * 8;
  float4 a = *(const float4*)(w + i);
  float4 b = *(const float4*)(w + i + 4);
  ushort8v v;
  v[0] = f2bf(a.x); v[1] = f2bf(a.y); v[2] = f2bf(a.z); v[3] = f2bf(a.w);
  v[4] = f2bf(b.x); v[5] = f2bf(b.y); v[6] = f2bf(b.z); v[7] = f2bf(b.w);
  *(ushort8v*)(wb + i) = v;
}

// ---------------------------------------------------------------------------
// Kernel 3: fused MoE GEMM, k-outer / h-inner, CLEAN SYNC (no inline asm).
//   out[r,c] = sum_h g[r,h]*(X[r,:]·W[h,c,:] + eb[h,c])
//            = sum_k sum_h g[r,h]*(A_k·B_{h,k})[r,c] + bias (fold is linear)
// BM=128 x BN=128, BK=64, 8 waves (2Mx4N, per-wave 64x32), grid=512.
// R4-R9 forensics: every build using raw s_barrier + asm-"memory" counted
// vmcnt spilled a constant ~4.5 dwords/lane/step (WRITE 619-916 MB,
// VGPR pinned at 128) regardless of which register array was removed;
// R1-R3 (plain __syncthreads sync) were all clean (WRITE 33 MB).  This
// round keeps the memory-optimal k-outer/h-inner fold structure and
// reverts the sync to the R1-proven form: simple A/B double buffers,
// stage-next THEN compute-current, ONE __syncthreads per step (compiler
// emits the vmcnt/lgkm drains).  m97-minimum pipeline: staging of step
// s+1 overlaps compute of step s.
// LDS = 2x16(A) + 2x16(B) + 4(g) + 4(eb) = 72 KB -> 2 blocks/CU
// (16 waves/CU; R9 was 1 block/CU), enabling cross-block overlap of the
// per-step drain (m114).
// Registers: acc[4][2](32) live across barriers; per kk-half transients
// af[4](16)+bf[2](8); per-step slice p[4][2](32) folded immediately
// (acc += g_h * p).  Peak ~105.
// Staging: linear LDS dest + inverse-swizzled global src; 3-bit XOR
// swizzle elem^=(row&7)<<3 on LDS reads (bank conflicts 0, R4-R9).
// col0 = (bx&7)*BN: XCD-affine -> 2MB W panel per XCD L2; X read once
// per block (k-outer), L3-shared across the 8 col-blocks of a row panel.
// ---------------------------------------------------------------------------
__global__ __launch_bounds__(512) void moe_gemm_kernel(
    const u16* __restrict__ Xb, const u16* __restrict__ Wb,
    const float* __restrict__ g, const float* __restrict__ eb,
    float* __restrict__ out) {
  __shared__ __align__(16) u16 As[2][BM * BK];   // 2 x 16 KB
  __shared__ __align__(16) u16 Bs[2][BN * BK];   // 2 x 16 KB
  __shared__ float gs[H_][BM];                   // gates (transposed), 4 KB
  __shared__ float ebs[H_][BN];                  // expert bias, 4 KB

  const int tid  = threadIdx.x;
  const int wave = tid >> 6;
  const int lane = tid & 63;

  const int bx   = blockIdx.x;          // 512 blocks; bx&7 -> XCD (W affinity)
  const int row0 = (bx >> 3) * BM;      // 64 row tiles
  const int col0 = (bx & 7) * BN;       // 8 col tiles

  // ---- stage g (transposed) and eb ----
  if (tid < BM) {
    const float* gr = g + (size_t)(row0 + tid) * H_;
#pragma unroll
    for (int h = 0; h < H_; ++h) gs[h][tid] = gr[h];
  }
  for (int i = tid; i < H_ * BN; i += 512) {
    int h = i >> 7, c = i & 127;
    ebs[h][c] = eb[h * O_ + col0 + c];
  }

  // ---- staging geometry: linear LDS dest, inverse-swizzled global src ----
  const int s_row = wave * 8 + (lane >> 3);
  const int s_col = ((lane & 7) * 8) ^ (((lane >> 3) & 7) << 3);
  const u16* a_base = Xb + (size_t)(row0 + s_row) * D_ + s_col;
  const int b_row   = col0 + s_row;
  const int lds_off = (wave * 8) * BK;   // elems, wave-uniform

#define STAGE_A(kk_, buf_)                                                     \
  {                                                                            \
    const u16* ap = a_base + (kk_) * BK;                                       \
    GLOAD16(ap,                    &As[buf_][lds_off]);                        \
    GLOAD16(ap + (size_t)64 * D_,  &As[buf_][lds_off + 64 * BK]);              \
  }
#define STAGE_B(hh_, kk_, sl_)                                                 \
  {                                                                            \
    const u16* bp = Wb + ((size_t)(hh_)*O_ + b_row) * D_ + (kk_)*BK + s_col;   \
    GLOAD16(bp,                    &Bs[sl_][lds_off]);                         \
    GLOAD16(bp + (size_t)64 * D_,  &Bs[sl_][lds_off + 64 * BK]);               \
  }

  // ---- swizzled LDS read offsets (elements) ----
  const int wm = wave >> 2;  // 0..1 : 64 rows
  const int wn = wave & 3;   // 0..3 : 32 cols
  const int sw  = (lane & 7) << 3;
  const int aq  = lane >> 4;
  const int ce0 = (aq * 8) ^ sw;
  const int ce1 = (aq * 8 + 32) ^ sw;
  const int arow0 = (wm * 64 + (lane & 15)) * BK;
  const int brow0 = (wn * 32 + (lane & 15)) * BK;

  const f32x4 zero4 = {0.f, 0.f, 0.f, 0.f};
  f32x4 acc[4][2];
#pragma unroll
  for (int i = 0; i < 4; ++i) { acc[i][0] = zero4; acc[i][1] = zero4; }

  // ---- prologue: stage (k=0,h=0) into A0/B0; drain via syncthreads ----
  STAGE_A(0, 0);
  STAGE_B(0, 0, 0);
  __syncthreads();

  for (int k = 0; k < KT; ++k) {
    const u16* Ab = &As[k & 1][0];
#pragma unroll
    for (int h = 0; h < H_; ++h) {
      // ---- stage NEXT step (overlaps this step's compute) ----
      if (h < H_ - 1) {
        STAGE_B(h + 1, k, (h + 1) & 1);
      } else if (k < KT - 1) {
        STAGE_B(0, k + 1, 0);
        STAGE_A(k + 1, (k + 1) & 1);
      }

      // ---- compute current step from As[k&1], Bs[h&1] ----
      const u16* Bb = &Bs[h & 1][0];
      f32x4 p[4][2];
      {
        short8 af0 = *(const short8*)&Ab[arow0 + 0 * 16 * BK + ce0];
        short8 af1 = *(const short8*)&Ab[arow0 + 1 * 16 * BK + ce0];
        short8 af2 = *(const short8*)&Ab[arow0 + 2 * 16 * BK + ce0];
        short8 af3 = *(const short8*)&Ab[arow0 + 3 * 16 * BK + ce0];
        short8 bfA = *(const short8*)&Bb[brow0 + ce0];
        short8 bfB = *(const short8*)&Bb[brow0 + 16 * BK + ce0];
        p[0][0] = __builtin_amdgcn_mfma_f32_16x16x32_bf16(af0, bfA, zero4, 0, 0, 0);
        p[0][1] = __builtin_amdgcn_mfma_f32_16x16x32_bf16(af0, bfB, zero4, 0, 0, 0);
        p[1][0] = __builtin_amdgcn_mfma_f32_16x16x32_bf16(af1, bfA, zero4, 0, 0, 0);
        p[1][1] = __builtin_amdgcn_mfma_f32_16x16x32_bf16(af1, bfB, zero4, 0, 0, 0);
        p[2][0] = __builtin_amdgcn_mfma_f32_16x16x32_bf16(af2, bfA, zero4, 0, 0, 0);
        p[2][1] = __builtin_amdgcn_mfma_f32_16x16x32_bf16(af2, bfB, zero4, 0, 0, 0);
        p[3][0] = __builtin_amdgcn_mfma_f32_16x16x32_bf16(af3, bfA, zero4, 0, 0, 0);
        p[3][1] = __builtin_amdgcn_mfma_f32_16x16x32_bf16(af3, bfB, zero4, 0, 0, 0);
      }
      {
        short8 af0 = *(const short8*)&Ab[arow0 + 0 * 16 * BK + ce1];
        short8 af1 = *(const short8*)&Ab[arow0 + 1 * 16 * BK + ce1];
        short8 af2 = *(const short8*)&Ab[arow0 + 2 * 16 * BK + ce1];
        short8 af3 = *(const short8*)&Ab[arow0 + 3 * 16 * BK + ce1];
        short8 bfA = *(const short8*)&Bb[brow0 + ce1];
        short8 bfB = *(const short8*)&Bb[brow0 + 16 * BK + ce1];
        p[0][0] = __builtin_amdgcn_mfma_f32_16x16x32_bf16(af0, bfA, p[0][0], 0, 0, 0);
        p[0][1] = __builtin_amdgcn_mfma_f32_16x16x32_bf16(af0, bfB, p[0][1], 0, 0, 0);
        p[1][0] = __builtin_amdgcn_mfma_f32_16x16x32_bf16(af1, bfA, p[1][0], 0, 0, 0);
        p[1][1] = __builtin_amdgcn_mfma_f32_16x16x32_bf16(af1, bfB, p[1][1], 0, 0, 0);
        p[2][0] = __builtin_amdgcn_mfma_f32_16x16x32_bf16(af2, bfA, p[2][0], 0, 0, 0);
        p[2][1] = __builtin_amdgcn_mfma_f32_16x16x32_bf16(af2, bfB, p[2][1], 0, 0, 0);
        p[3][0] = __builtin_amdgcn_mfma_f32_16x16x32_bf16(af3, bfA, p[3][0], 0, 0, 0);
        p[3][1] = __builtin_amdgcn_mfma_f32_16x16x32_bf16(af3, bfB, p[3][1], 0, 0, 0);
      }

      // ---- immediate fold: acc += g_h * p ----
#pragma unroll
      for (int fm = 0; fm < 4; ++fm) {
        const f32x4 gg =
            *(const f32x4*)&gs[h][wm * 64 + fm * 16 + (lane >> 4) * 4];
#pragma unroll
        for (int j = 0; j < 4; ++j) {
          acc[fm][0][j] += gg[j] * p[fm][0][j];
          acc[fm][1][j] += gg[j] * p[fm][1][j];
        }
      }

      __syncthreads();   // drains this step's stages; next step may read them
    }
  }

  // ---- epilogue: C/D layout col = lane&15, row = (lane>>4)*4 + j ----
  const int crow_l = wm * 64 + (lane >> 4) * 4;
  const int ccol_l = wn * 32 + (lane & 15);
#pragma unroll
  for (int fm = 0; fm < 4; ++fm) {
#pragma unroll
    for (int fn = 0; fn < 2; ++fn) {
#pragma unroll
      for (int j = 0; j < 4; ++j) {
        float b = 0.f;
#pragma unroll
        for (int h = 0; h < H_; ++h)
          b += gs[h][crow_l + fm * 16 + j] * ebs[h][ccol_l + fn * 16];
        out[(size_t)(row0 + crow_l + fm * 16 + j) * O_ +
            (col0 + ccol_l + fn * 16)] = acc[fm][fn][j] + b;
      }
    }
  }
}

// ---------------------------------------------------------------------------
extern "C" void kernel_launch(void* const* d_in, const int* in_sizes, int n_in,
                              void* d_out, int out_size, void* d_ws,
                              size_t ws_size, hipStream_t stream) {
  const float* x   = (const float*)d_in[0];
  const float* gw  = (const float*)d_in[1];
  const float* gb  = (const float*)d_in[2];
  const float* ew  = (const float*)d_in[3];
  const float* ebp = (const float*)d_in[4];
  float* out = (float*)d_out;

  u16*   x_bf = (u16*)d_ws;                                            // 16 MB
  u16*   w_bf = (u16*)((char*)d_ws + (size_t)BS_ * D_ * 2);            // 16 MB
  float* gbuf = (float*)((char*)d_ws + (size_t)BS_ * D_ * 2 +
                         (size_t)H_ * O_ * D_ * 2);                    // 256 KB

  gate_conv_kernel<<<BS_ / 4, 256, 0, stream>>>(x, gw, gb, x_bf, gbuf);
  convw_kernel<<<(H_ * O_ * D_) / 2048, 256, 0, stream>>>(ew, w_bf);
  moe_gemm_kernel<<<(BS_ / BM) * (O_ / BN), 512, 0, stream>>>(x_bf, w_bf, gbuf,
                                                              ebp, out);
}

// Round 11
// 172.151 us; speedup vs baseline: 5.5225x; 5.5225x over previous
//
#include <hip/hip_runtime.h>
#include <hip/hip_bf16.h>
#include <stdint.h>

#define B_  4
#define S_  2048
#define BS_ (B_ * S_)   // 8192 tokens
#define D_  1024
#define O_  1024
#define H_  8

#define BM 256
#define BN 128
#define BK 64
#define NT 128          // K' tiles: (h,k) combined, 8*1024/64

typedef unsigned short u16;
typedef __attribute__((ext_vector_type(8))) short     short8;
typedef __attribute__((ext_vector_type(8))) unsigned short ushort8v;
typedef __attribute__((ext_vector_type(4))) float     f32x4;

__device__ __forceinline__ u16 f2bf(float f) {
  unsigned u = __float_as_uint(f);
  unsigned r = (u + 0x7fffu + ((u >> 16) & 1u)) >> 16;
  return (u16)r;
}

#define GLOAD16(gp, lp)                                                        \
  __builtin_amdgcn_global_load_lds(                                            \
      (const __attribute__((address_space(1))) void*)(gp),                     \
      (__attribute__((address_space(3))) void*)(lp), 16, 0, 0)

// ---------------------------------------------------------------------------
// Kernel 1: gates (f32, one wave per token) + x -> bf16 conversion
// ---------------------------------------------------------------------------
__global__ __launch_bounds__(256) void gate_conv_kernel(
    const float* __restrict__ x, const float* __restrict__ gate_w,
    const float* __restrict__ gate_b, u16* __restrict__ x_bf,
    float* __restrict__ g_out) {
  const int wave  = threadIdx.x >> 6;
  const int lane  = threadIdx.x & 63;
  const int token = blockIdx.x * 4 + wave;
  const float* xr = x + (size_t)token * D_;
  const int d0 = lane * 16;

  float4 xv[4];
#pragma unroll
  for (int i = 0; i < 4; ++i) xv[i] = *(const float4*)(xr + d0 + i * 4);

  ushort8v lo, hi;
#pragma unroll
  for (int i = 0; i < 2; ++i) {
    lo[i * 4 + 0] = f2bf(xv[i].x); lo[i * 4 + 1] = f2bf(xv[i].y);
    lo[i * 4 + 2] = f2bf(xv[i].z); lo[i * 4 + 3] = f2bf(xv[i].w);
    hi[i * 4 + 0] = f2bf(xv[2 + i].x); hi[i * 4 + 1] = f2bf(xv[2 + i].y);
    hi[i * 4 + 2] = f2bf(xv[2 + i].z); hi[i * 4 + 3] = f2bf(xv[2 + i].w);
  }
  *(ushort8v*)(x_bf + (size_t)token * D_ + d0) = lo;
  *(ushort8v*)(x_bf + (size_t)token * D_ + d0 + 8) = hi;

  float s[H_];
#pragma unroll
  for (int h = 0; h < H_; ++h) {
    const float* gw = gate_w + h * D_ + d0;
    float a = 0.f;
#pragma unroll
    for (int i = 0; i < 4; ++i) {
      float4 w = *(const float4*)(gw + i * 4);
      a += xv[i].x * w.x + xv[i].y * w.y + xv[i].z * w.z + xv[i].w * w.w;
    }
    s[h] = a;
  }
#pragma unroll
  for (int h = 0; h < H_; ++h) {
#pragma unroll
    for (int off = 32; off > 0; off >>= 1) s[h] += __shfl_xor(s[h], off);
    s[h] += gate_b[h];
  }
  float m = s[0];
#pragma unroll
  for (int h = 1; h < H_; ++h) m = fmaxf(m, s[h]);
  float sum = 0.f;
#pragma unroll
  for (int h = 0; h < H_; ++h) { s[h] = expf(s[h] - m); sum += s[h]; }
  const float inv = 1.0f / sum;
#pragma unroll
  for (int h = 0; h < H_; ++h) s[h] *= inv;

  if (lane == 0) {
    float4 g0 = make_float4(s[0], s[1], s[2], s[3]);
    float4 g1 = make_float4(s[4], s[5], s[6], s[7]);
    *(float4*)(g_out + (size_t)token * H_)     = g0;
    *(float4*)(g_out + (size_t)token * H_ + 4) = g1;
  }
}

// ---------------------------------------------------------------------------
// Kernel 2: expert_w f32 -> bf16
// ---------------------------------------------------------------------------
__global__ __launch_bounds__(256) void convw_kernel(
    const float* __restrict__ w, u16* __restrict__ wb) {
  size_t i = ((size_t)blockIdx.x * 256 + threadIdx.x) * 8;
  float4 a = *(const float4*)(w + i);
  float4 b = *(const float4*)(w + i + 4);
  ushort8v v;
  v[0] = f2bf(a.x); v[1] = f2bf(a.y); v[2] = f2bf(a.z); v[3] = f2bf(a.w);
  v[4] = f2bf(b.x); v[5] = f2bf(b.y); v[6] = f2bf(b.z); v[7] = f2bf(b.w);
  *(ushort8v*)(wb + i) = v;
}

// ---------------------------------------------------------------------------
// Kernel 3: fused MoE GEMM == R3 (best measured: 186us, VGPR 96, no spill)
// with exactly TWO fixes:
//  (a) verified 3-bit XOR swizzle elem^=(row&7)<<3 (R3's 2-bit had 2.1e7
//      conflicts; 3-bit measured 0 across R4-R10 on identical geometry);
//  (b) XCD = row-panel-group remap: XCD c owns row panels 4c..4c+3
//      (A: 4x512KB = 2MB, stays L2-resident the WHOLE kernel since all
//      8 col-blocks of a panel re-read it every h) x 8 col-blocks that
//      march h in lockstep (W[h] = 2MB, L2-shared per XCD).  R3's XCD=col
//      mapping had 32 distinct A panels (16MB) per XCD thrash L2 ->
//      533MB re-stream at 3.1TB/s = the measured 186us limiter.
// Structure (unchanged from R3): BM=256 x BN=128, BK=64, 8 waves (2Mx4N,
// per-wave 128x32), grid=256 (1 block/CU), h-outer t=(h,k) walk, 3-deep
// LDS ring, 2 phases/tile (A-prefetch@phase0, B-prefetch@phase1, t+2
// ahead), counted vmcnt(6) (never 0 mid-loop), setprio around MFMA,
// per-h fold acc += g_h*(part+eb), part reset at h-boundary.
// ---------------------------------------------------------------------------
__global__ __launch_bounds__(512, 2) void moe_gemm_kernel(
    const u16* __restrict__ Xb, const u16* __restrict__ Wb,
    const float* __restrict__ g, const float* __restrict__ eb,
    float* __restrict__ out) {
  __shared__ __align__(16) u16 As[3][BM * BK];   // 3 x 32 KB
  __shared__ __align__(16) u16 Bs[3][BN * BK];   // 3 x 16 KB
  __shared__ float gs[H_][BM];                   // 8 KB, transposed
  __shared__ float ebs[H_][BN];                  // 4 KB

  const int tid  = threadIdx.x;
  const int wave = tid >> 6;
  const int lane = tid & 63;

  // ---- XCD-affine mapping: xcd = bx&7 owns row panels 4*(bx&7)+ (bx>>6) ----
  const int bx   = blockIdx.x;                 // 256 blocks
  const int row0 = ((bx & 7) * 4 + (bx >> 6)) * BM;   // 32 row panels
  const int col0 = ((bx >> 3) & 7) * BN;               // 8 col panels

  for (int i = tid; i < H_ * BM; i += 512) {
    int h = i >> 8, r = i & 255;
    gs[h][r] = g[(size_t)(row0 + r) * H_ + h];
  }
  for (int i = tid; i < H_ * BN; i += 512) {
    int h = i >> 7, c = i & 127;
    ebs[h][c] = eb[h * O_ + col0 + c];
  }

  const int wm = wave >> 2;  // 0..1 : 128 rows
  const int wn = wave & 3;   // 0..3 : 32 cols

  // ---- staging source (inverse-swizzled global addr; LDS dest linear) ----
  // involution: elem_col ^= (row&7)<<3 ; staged row&7 == (lane>>3)&7
  const int s_row = wave * 8 + (lane >> 3);               // row in 64-group
  const int s_col = ((lane & 7) * 8) ^ (((lane >> 3) & 7) << 3);
  const u16* a_base = Xb + (size_t)(row0 + s_row) * D_ + s_col;
  const u16* b_base = Wb + (size_t)(col0 + s_row) * D_ + s_col;
  const int lds_off = (wave * 8) * BK;                    // elems, wave-uniform

  // ---- swizzled LDS read offsets (elements); read row&7 == lane&7 ----
  const int sw  = (lane & 7) << 3;
  const int aq  = lane >> 4;
  const int ce0 = (aq * 8) ^ sw;
  const int ce1 = (aq * 8 + 32) ^ sw;
  const int arow = (wm * 128 + (lane & 15)) * BK;
  const int brow = (wn * 32  + (lane & 15)) * BK;

  const f32x4 zero4 = {0.f, 0.f, 0.f, 0.f};
  f32x4 acc[8][2], part[8][2];
#pragma unroll
  for (int i = 0; i < 8; ++i)
#pragma unroll
    for (int j = 0; j < 2; ++j) { acc[i][j] = zero4; part[i][j] = zero4; }

  // ---- prologue: stage tiles 0 and 1 (both h=0) ----
#pragma unroll
  for (int i = 0; i < 4; ++i)
    GLOAD16(a_base + (size_t)(i * 64) * D_, &As[0][lds_off + i * 64 * BK]);
#pragma unroll
  for (int j = 0; j < 2; ++j)
    GLOAD16(b_base + (size_t)(j * 64) * D_, &Bs[0][lds_off + j * 64 * BK]);
#pragma unroll
  for (int i = 0; i < 4; ++i)
    GLOAD16(a_base + (size_t)(i * 64) * D_ + 64, &As[1][lds_off + i * 64 * BK]);
#pragma unroll
  for (int j = 0; j < 2; ++j)
    GLOAD16(b_base + (size_t)(j * 64) * D_ + 64, &Bs[1][lds_off + j * 64 * BK]);

  asm volatile("s_waitcnt vmcnt(6) lgkmcnt(0)" ::: "memory");
  __builtin_amdgcn_s_barrier();

  int buf = 0;
  for (int t = 0; t < NT; ++t) {
    const u16* Ab = &As[buf][0];
    const u16* Bb = &Bs[buf][0];
    const int t2 = t + 2;
    const int sbuf = (buf + 2 >= 3) ? buf - 1 : buf + 2;

    short8 af[8], bfr[2];

    // ============ phase 0 (kk=0) ============
#pragma unroll
    for (int fm = 0; fm < 8; ++fm)
      af[fm] = *(const short8*)&Ab[arow + fm * 16 * BK + ce0];
#pragma unroll
    for (int fn = 0; fn < 2; ++fn)
      bfr[fn] = *(const short8*)&Bb[brow + fn * 16 * BK + ce0];

    if (t2 < NT) {  // prefetch A of tile t+2
      const size_t koff = (size_t)((t2 & 15) * 64);
#pragma unroll
      for (int i = 0; i < 4; ++i)
        GLOAD16(a_base + (size_t)(i * 64) * D_ + koff,
                &As[sbuf][lds_off + i * 64 * BK]);
    }
    __builtin_amdgcn_s_barrier();
    __builtin_amdgcn_s_setprio(1);
#pragma unroll
    for (int fm = 0; fm < 8; ++fm) {
      part[fm][0] = __builtin_amdgcn_mfma_f32_16x16x32_bf16(
          af[fm], bfr[0], part[fm][0], 0, 0, 0);
      part[fm][1] = __builtin_amdgcn_mfma_f32_16x16x32_bf16(
          af[fm], bfr[1], part[fm][1], 0, 0, 0);
    }
    __builtin_amdgcn_s_setprio(0);
    __builtin_amdgcn_s_barrier();

    // ============ phase 1 (kk=1) ============
#pragma unroll
    for (int fm = 0; fm < 8; ++fm)
      af[fm] = *(const short8*)&Ab[arow + fm * 16 * BK + ce1];
#pragma unroll
    for (int fn = 0; fn < 2; ++fn)
      bfr[fn] = *(const short8*)&Bb[brow + fn * 16 * BK + ce1];

    if (t2 < NT) {  // prefetch B of tile t+2
      const size_t boff = ((size_t)(t2 >> 4) * O_) * D_ + (size_t)((t2 & 15) * 64);
#pragma unroll
      for (int j = 0; j < 2; ++j)
        GLOAD16(b_base + (size_t)(j * 64) * D_ + boff,
                &Bs[sbuf][lds_off + j * 64 * BK]);
    }
    __builtin_amdgcn_s_barrier();
    __builtin_amdgcn_s_setprio(1);
#pragma unroll
    for (int fm = 0; fm < 8; ++fm) {
      part[fm][0] = __builtin_amdgcn_mfma_f32_16x16x32_bf16(
          af[fm], bfr[0], part[fm][0], 0, 0, 0);
      part[fm][1] = __builtin_amdgcn_mfma_f32_16x16x32_bf16(
          af[fm], bfr[1], part[fm][1], 0, 0, 0);
    }
    __builtin_amdgcn_s_setprio(0);

    if (t < NT - 2) {
      asm volatile("s_waitcnt vmcnt(6)" ::: "memory");  // t+1 ready, t+2 in flight
    } else {
      asm volatile("s_waitcnt vmcnt(0)" ::: "memory");
    }
    __builtin_amdgcn_s_barrier();

    // ============ fold at end of each expert h ============
    if ((t & 15) == 15) {
      const int h = t >> 4;
      const float ebv0 = ebs[h][wn * 32 + (lane & 15)];
      const float ebv1 = ebs[h][wn * 32 + 16 + (lane & 15)];
#pragma unroll
      for (int fm = 0; fm < 8; ++fm) {
        const f32x4 gg = *(const f32x4*)&gs[h][wm * 128 + fm * 16 + (lane >> 4) * 4];
#pragma unroll
        for (int j = 0; j < 4; ++j) {
          acc[fm][0][j] += gg[j] * (part[fm][0][j] + ebv0);
          acc[fm][1][j] += gg[j] * (part[fm][1][j] + ebv1);
          part[fm][0][j] = 0.f;
          part[fm][1][j] = 0.f;
        }
      }
    }

    buf = (buf == 2) ? 0 : buf + 1;
  }

  // ---- epilogue: C/D layout col = lane&15, row = (lane>>4)*4 + j ----
  const int crow = row0 + wm * 128 + (lane >> 4) * 4;
  const int ccol = col0 + wn * 32 + (lane & 15);
#pragma unroll
  for (int fm = 0; fm < 8; ++fm)
#pragma unroll
    for (int fn = 0; fn < 2; ++fn)
#pragma unroll
      for (int j = 0; j < 4; ++j)
        out[(size_t)(crow + fm * 16 + j) * O_ + (ccol + fn * 16)] =
            acc[fm][fn][j];
}

// ---------------------------------------------------------------------------
extern "C" void kernel_launch(void* const* d_in, const int* in_sizes, int n_in,
                              void* d_out, int out_size, void* d_ws,
                              size_t ws_size, hipStream_t stream) {
  const float* x   = (const float*)d_in[0];
  const float* gw  = (const float*)d_in[1];
  const float* gb  = (const float*)d_in[2];
  const float* ew  = (const float*)d_in[3];
  const float* ebp = (const float*)d_in[4];
  float* out = (float*)d_out;

  u16*   x_bf = (u16*)d_ws;                                            // 16 MB
  u16*   w_bf = (u16*)((char*)d_ws + (size_t)BS_ * D_ * 2);            // 16 MB
  float* gbuf = (float*)((char*)d_ws + (size_t)BS_ * D_ * 2 +
                         (size_t)H_ * O_ * D_ * 2);                    // 256 KB

  gate_conv_kernel<<<BS_ / 4, 256, 0, stream>>>(x, gw, gb, x_bf, gbuf);
  convw_kernel<<<(H_ * O_ * D_) / 2048, 256, 0, stream>>>(ew, w_bf);
  moe_gemm_kernel<<<(BS_ / BM) * (O_ / BN), 512, 0, stream>>>(x_bf, w_bf, gbuf,
                                                              ebp, out);
}

// Round 12
// 168.032 us; speedup vs baseline: 5.6579x; 1.0245x over previous
//
#include <hip/hip_runtime.h>
#include <hip/hip_bf16.h>
#include <stdint.h>

#define B_  4
#define S_  2048
#define BS_ (B_ * S_)   // 8192 tokens
#define D_  1024
#define O_  1024
#define H_  8

#define BM 256
#define BN 128
#define BK 64
#define NT 128          // K' tiles: (h,k) combined, 8*1024/64

typedef unsigned short u16;
typedef __attribute__((ext_vector_type(8))) short     short8;
typedef __attribute__((ext_vector_type(8))) unsigned short ushort8v;
typedef __attribute__((ext_vector_type(4))) float     f32x4;

__device__ __forceinline__ u16 f2bf(float f) {
  unsigned u = __float_as_uint(f);
  unsigned r = (u + 0x7fffu + ((u >> 16) & 1u)) >> 16;
  return (u16)r;
}

#define GLOAD16(gp, lp)                                                        \
  __builtin_amdgcn_global_load_lds(                                            \
      (const __attribute__((address_space(1))) void*)(gp),                     \
      (__attribute__((address_space(3))) void*)(lp), 16, 0, 0)

// ---------------------------------------------------------------------------
// Kernel 1: gates (f32, one wave per token) + x -> bf16 conversion
// ---------------------------------------------------------------------------
__global__ __launch_bounds__(256) void gate_conv_kernel(
    const float* __restrict__ x, const float* __restrict__ gate_w,
    const float* __restrict__ gate_b, u16* __restrict__ x_bf,
    float* __restrict__ g_out) {
  const int wave  = threadIdx.x >> 6;
  const int lane  = threadIdx.x & 63;
  const int token = blockIdx.x * 4 + wave;
  const float* xr = x + (size_t)token * D_;
  const int d0 = lane * 16;

  float4 xv[4];
#pragma unroll
  for (int i = 0; i < 4; ++i) xv[i] = *(const float4*)(xr + d0 + i * 4);

  ushort8v lo, hi;
#pragma unroll
  for (int i = 0; i < 2; ++i) {
    lo[i * 4 + 0] = f2bf(xv[i].x); lo[i * 4 + 1] = f2bf(xv[i].y);
    lo[i * 4 + 2] = f2bf(xv[i].z); lo[i * 4 + 3] = f2bf(xv[i].w);
    hi[i * 4 + 0] = f2bf(xv[2 + i].x); hi[i * 4 + 1] = f2bf(xv[2 + i].y);
    hi[i * 4 + 2] = f2bf(xv[2 + i].z); hi[i * 4 + 3] = f2bf(xv[2 + i].w);
  }
  *(ushort8v*)(x_bf + (size_t)token * D_ + d0) = lo;
  *(ushort8v*)(x_bf + (size_t)token * D_ + d0 + 8) = hi;

  float s[H_];
#pragma unroll
  for (int h = 0; h < H_; ++h) {
    const float* gw = gate_w + h * D_ + d0;
    float a = 0.f;
#pragma unroll
    for (int i = 0; i < 4; ++i) {
      float4 w = *(const float4*)(gw + i * 4);
      a += xv[i].x * w.x + xv[i].y * w.y + xv[i].z * w.z + xv[i].w * w.w;
    }
    s[h] = a;
  }
#pragma unroll
  for (int h = 0; h < H_; ++h) {
#pragma unroll
    for (int off = 32; off > 0; off >>= 1) s[h] += __shfl_xor(s[h], off);
    s[h] += gate_b[h];
  }
  float m = s[0];
#pragma unroll
  for (int h = 1; h < H_; ++h) m = fmaxf(m, s[h]);
  float sum = 0.f;
#pragma unroll
  for (int h = 0; h < H_; ++h) { s[h] = expf(s[h] - m); sum += s[h]; }
  const float inv = 1.0f / sum;
#pragma unroll
  for (int h = 0; h < H_; ++h) s[h] *= inv;

  if (lane == 0) {
    float4 g0 = make_float4(s[0], s[1], s[2], s[3]);
    float4 g1 = make_float4(s[4], s[5], s[6], s[7]);
    *(float4*)(g_out + (size_t)token * H_)     = g0;
    *(float4*)(g_out + (size_t)token * H_ + 4) = g1;
  }
}

// ---------------------------------------------------------------------------
// Kernel 2: expert_w f32 -> bf16
// ---------------------------------------------------------------------------
__global__ __launch_bounds__(256) void convw_kernel(
    const float* __restrict__ w, u16* __restrict__ wb) {
  size_t i = ((size_t)blockIdx.x * 256 + threadIdx.x) * 8;
  float4 a = *(const float4*)(w + i);
  float4 b = *(const float4*)(w + i + 4);
  ushort8v v;
  v[0] = f2bf(a.x); v[1] = f2bf(a.y); v[2] = f2bf(a.z); v[3] = f2bf(a.w);
  v[4] = f2bf(b.x); v[5] = f2bf(b.y); v[6] = f2bf(b.z); v[7] = f2bf(b.w);
  *(ushort8v*)(wb + i) = v;
}

// ---------------------------------------------------------------------------
// Kernel 3: fused MoE GEMM == R11 (161us GEMM, 0 conflicts, FETCH 99MB,
// VGPR 96, no spill) with ONE parameter change: wave grid 2Mx4N -> 4Mx2N
// (per-wave tile 128x32 -> 64x64, same area).
// WHY: R11's LDS-read budget was the limiter -- 20 b128/wave/K-tile (A:16
// B:4) = ~640 LDS-cyc/CU vs 307 MFMA-cyc -> MfmaUtil ceiling ~48% (measured
// 36).  Square 64x64 wave tile: 16 b128/K-tile (A:8 B:8) = ~512 cyc ->
// ceiling ~60%.  acc[4][4]+part[4][4] = same 128 regs as R11's [8][2].
// Everything else untouched: h-outer t=(h,k) walk, 3-deep LDS ring, 2
// phases/tile, t+2 prefetch (A@phase0, B@phase1), counted vmcnt(6) (never
// 0 mid-loop), setprio around MFMA, 3-bit XOR swizzle elem^=(row&7)<<3
// (0 conflicts), XCD = row-panel-group mapping (A panel 2MB L2-pinned per
// XCD; FETCH 533->99MB verified), per-h fold acc += g_h*(part+eb).
// ---------------------------------------------------------------------------
__global__ __launch_bounds__(512, 2) void moe_gemm_kernel(
    const u16* __restrict__ Xb, const u16* __restrict__ Wb,
    const float* __restrict__ g, const float* __restrict__ eb,
    float* __restrict__ out) {
  __shared__ __align__(16) u16 As[3][BM * BK];   // 3 x 32 KB
  __shared__ __align__(16) u16 Bs[3][BN * BK];   // 3 x 16 KB
  __shared__ float gs[H_][BM];                   // 8 KB, transposed
  __shared__ float ebs[H_][BN];                  // 4 KB

  const int tid  = threadIdx.x;
  const int wave = tid >> 6;
  const int lane = tid & 63;

  // ---- XCD-affine mapping: xcd = bx&7 owns row panels 4*(bx&7)+(bx>>6) ----
  const int bx   = blockIdx.x;                 // 256 blocks
  const int row0 = ((bx & 7) * 4 + (bx >> 6)) * BM;   // 32 row panels
  const int col0 = ((bx >> 3) & 7) * BN;               // 8 col panels

  for (int i = tid; i < H_ * BM; i += 512) {
    int h = i >> 8, r = i & 255;
    gs[h][r] = g[(size_t)(row0 + r) * H_ + h];
  }
  for (int i = tid; i < H_ * BN; i += 512) {
    int h = i >> 7, c = i & 127;
    ebs[h][c] = eb[h * O_ + col0 + c];
  }

  const int wm = wave >> 1;  // 0..3 : 64-row band
  const int wn = wave & 1;   // 0..1 : 64-col band

  // ---- staging source (inverse-swizzled global addr; LDS dest linear) ----
  // involution: elem_col ^= (row&7)<<3 ; staged row&7 == (lane>>3)&7
  const int s_row = wave * 8 + (lane >> 3);               // row in 64-group
  const int s_col = ((lane & 7) * 8) ^ (((lane >> 3) & 7) << 3);
  const u16* a_base = Xb + (size_t)(row0 + s_row) * D_ + s_col;
  const u16* b_base = Wb + (size_t)(col0 + s_row) * D_ + s_col;
  const int lds_off = (wave * 8) * BK;                    // elems, wave-uniform

  // ---- swizzled LDS read offsets (elements); read row&7 == lane&7 ----
  const int sw  = (lane & 7) << 3;
  const int aq  = lane >> 4;
  const int ce0 = (aq * 8) ^ sw;
  const int ce1 = (aq * 8 + 32) ^ sw;
  const int arow = (wm * 64 + (lane & 15)) * BK;
  const int brow = (wn * 64 + (lane & 15)) * BK;

  const f32x4 zero4 = {0.f, 0.f, 0.f, 0.f};
  f32x4 acc[4][4], part[4][4];
#pragma unroll
  for (int i = 0; i < 4; ++i)
#pragma unroll
    for (int j = 0; j < 4; ++j) { acc[i][j] = zero4; part[i][j] = zero4; }

  // ---- prologue: stage tiles 0 and 1 (both h=0) ----
#pragma unroll
  for (int i = 0; i < 4; ++i)
    GLOAD16(a_base + (size_t)(i * 64) * D_, &As[0][lds_off + i * 64 * BK]);
#pragma unroll
  for (int j = 0; j < 2; ++j)
    GLOAD16(b_base + (size_t)(j * 64) * D_, &Bs[0][lds_off + j * 64 * BK]);
#pragma unroll
  for (int i = 0; i < 4; ++i)
    GLOAD16(a_base + (size_t)(i * 64) * D_ + 64, &As[1][lds_off + i * 64 * BK]);
#pragma unroll
  for (int j = 0; j < 2; ++j)
    GLOAD16(b_base + (size_t)(j * 64) * D_ + 64, &Bs[1][lds_off + j * 64 * BK]);

  asm volatile("s_waitcnt vmcnt(6) lgkmcnt(0)" ::: "memory");
  __builtin_amdgcn_s_barrier();

  int buf = 0;
  for (int t = 0; t < NT; ++t) {
    const u16* Ab = &As[buf][0];
    const u16* Bb = &Bs[buf][0];
    const int t2 = t + 2;
    const int sbuf = (buf + 2 >= 3) ? buf - 1 : buf + 2;

    short8 af[4], bfr[4];

    // ============ phase 0 (kk=0) ============
#pragma unroll
    for (int fm = 0; fm < 4; ++fm)
      af[fm] = *(const short8*)&Ab[arow + fm * 16 * BK + ce0];
#pragma unroll
    for (int fn = 0; fn < 4; ++fn)
      bfr[fn] = *(const short8*)&Bb[brow + fn * 16 * BK + ce0];

    if (t2 < NT) {  // prefetch A of tile t+2
      const size_t koff = (size_t)((t2 & 15) * 64);
#pragma unroll
      for (int i = 0; i < 4; ++i)
        GLOAD16(a_base + (size_t)(i * 64) * D_ + koff,
                &As[sbuf][lds_off + i * 64 * BK]);
    }
    __builtin_amdgcn_s_barrier();
    __builtin_amdgcn_s_setprio(1);
#pragma unroll
    for (int fm = 0; fm < 4; ++fm)
#pragma unroll
      for (int fn = 0; fn < 4; ++fn)
        part[fm][fn] = __builtin_amdgcn_mfma_f32_16x16x32_bf16(
            af[fm], bfr[fn], part[fm][fn], 0, 0, 0);
    __builtin_amdgcn_s_setprio(0);
    __builtin_amdgcn_s_barrier();

    // ============ phase 1 (kk=1) ============
#pragma unroll
    for (int fm = 0; fm < 4; ++fm)
      af[fm] = *(const short8*)&Ab[arow + fm * 16 * BK + ce1];
#pragma unroll
    for (int fn = 0; fn < 4; ++fn)
      bfr[fn] = *(const short8*)&Bb[brow + fn * 16 * BK + ce1];

    if (t2 < NT) {  // prefetch B of tile t+2
      const size_t boff = ((size_t)(t2 >> 4) * O_) * D_ + (size_t)((t2 & 15) * 64);
#pragma unroll
      for (int j = 0; j < 2; ++j)
        GLOAD16(b_base + (size_t)(j * 64) * D_ + boff,
                &Bs[sbuf][lds_off + j * 64 * BK]);
    }
    __builtin_amdgcn_s_barrier();
    __builtin_amdgcn_s_setprio(1);
#pragma unroll
    for (int fm = 0; fm < 4; ++fm)
#pragma unroll
      for (int fn = 0; fn < 4; ++fn)
        part[fm][fn] = __builtin_amdgcn_mfma_f32_16x16x32_bf16(
            af[fm], bfr[fn], part[fm][fn], 0, 0, 0);
    __builtin_amdgcn_s_setprio(0);

    if (t < NT - 2) {
      asm volatile("s_waitcnt vmcnt(6)" ::: "memory");  // t+1 ready, t+2 in flight
    } else {
      asm volatile("s_waitcnt vmcnt(0)" ::: "memory");
    }
    __builtin_amdgcn_s_barrier();

    // ============ fold at end of each expert h ============
    if ((t & 15) == 15) {
      const int h = t >> 4;
      float ebv[4];
#pragma unroll
      for (int fn = 0; fn < 4; ++fn)
        ebv[fn] = ebs[h][wn * 64 + fn * 16 + (lane & 15)];
#pragma unroll
      for (int fm = 0; fm < 4; ++fm) {
        const f32x4 gg =
            *(const f32x4*)&gs[h][wm * 64 + fm * 16 + (lane >> 4) * 4];
#pragma unroll
        for (int fn = 0; fn < 4; ++fn)
#pragma unroll
          for (int j = 0; j < 4; ++j) {
            acc[fm][fn][j] += gg[j] * (part[fm][fn][j] + ebv[fn]);
            part[fm][fn][j] = 0.f;
          }
      }
    }

    buf = (buf == 2) ? 0 : buf + 1;
  }

  // ---- epilogue: C/D layout col = lane&15, row = (lane>>4)*4 + j ----
  const int crow = row0 + wm * 64 + (lane >> 4) * 4;
  const int ccol = col0 + wn * 64 + (lane & 15);
#pragma unroll
  for (int fm = 0; fm < 4; ++fm)
#pragma unroll
    for (int fn = 0; fn < 4; ++fn)
#pragma unroll
      for (int j = 0; j < 4; ++j)
        out[(size_t)(crow + fm * 16 + j) * O_ + (ccol + fn * 16)] =
            acc[fm][fn][j];
}

// ---------------------------------------------------------------------------
extern "C" void kernel_launch(void* const* d_in, const int* in_sizes, int n_in,
                              void* d_out, int out_size, void* d_ws,
                              size_t ws_size, hipStream_t stream) {
  const float* x   = (const float*)d_in[0];
  const float* gw  = (const float*)d_in[1];
  const float* gb  = (const float*)d_in[2];
  const float* ew  = (const float*)d_in[3];
  const float* ebp = (const float*)d_in[4];
  float* out = (float*)d_out;

  u16*   x_bf = (u16*)d_ws;                                            // 16 MB
  u16*   w_bf = (u16*)((char*)d_ws + (size_t)BS_ * D_ * 2);            // 16 MB
  float* gbuf = (float*)((char*)d_ws + (size_t)BS_ * D_ * 2 +
                         (size_t)H_ * O_ * D_ * 2);                    // 256 KB

  gate_conv_kernel<<<BS_ / 4, 256, 0, stream>>>(x, gw, gb, x_bf, gbuf);
  convw_kernel<<<(H_ * O_ * D_) / 2048, 256, 0, stream>>>(ew, w_bf);
  moe_gemm_kernel<<<(BS_ / BM) * (O_ / BN), 512, 0, stream>>>(x_bf, w_bf, gbuf,
                                                              ebp, out);
}

// Round 13
// 158.324 us; speedup vs baseline: 6.0049x; 1.0613x over previous
//
#include <hip/hip_runtime.h>
#include <hip/hip_bf16.h>
#include <stdint.h>

#define B_  4
#define S_  2048
#define BS_ (B_ * S_)   // 8192 tokens
#define D_  1024
#define O_  1024
#define H_  8

#define BM 256
#define BN 128
#define BK 64
#define NT 128          // K' tiles: (h,k) combined, 8*1024/64

typedef unsigned short u16;
typedef __attribute__((ext_vector_type(8))) short     short8;
typedef __attribute__((ext_vector_type(8))) unsigned short ushort8v;
typedef __attribute__((ext_vector_type(4))) float     f32x4;

__device__ __forceinline__ u16 f2bf(float f) {
  unsigned u = __float_as_uint(f);
  unsigned r = (u + 0x7fffu + ((u >> 16) & 1u)) >> 16;
  return (u16)r;
}

#define GLOAD16(gp, lp)                                                        \
  __builtin_amdgcn_global_load_lds(                                            \
      (const __attribute__((address_space(1))) void*)(gp),                     \
      (__attribute__((address_space(3))) void*)(lp), 16, 0, 0)

// ---------------------------------------------------------------------------
// Kernel 1: gates (f32, one wave per token) + x -> bf16 conversion
// ---------------------------------------------------------------------------
__global__ __launch_bounds__(256) void gate_conv_kernel(
    const float* __restrict__ x, const float* __restrict__ gate_w,
    const float* __restrict__ gate_b, u16* __restrict__ x_bf,
    float* __restrict__ g_out) {
  const int wave  = threadIdx.x >> 6;
  const int lane  = threadIdx.x & 63;
  const int token = blockIdx.x * 4 + wave;
  const float* xr = x + (size_t)token * D_;
  const int d0 = lane * 16;

  float4 xv[4];
#pragma unroll
  for (int i = 0; i < 4; ++i) xv[i] = *(const float4*)(xr + d0 + i * 4);

  ushort8v lo, hi;
#pragma unroll
  for (int i = 0; i < 2; ++i) {
    lo[i * 4 + 0] = f2bf(xv[i].x); lo[i * 4 + 1] = f2bf(xv[i].y);
    lo[i * 4 + 2] = f2bf(xv[i].z); lo[i * 4 + 3] = f2bf(xv[i].w);
    hi[i * 4 + 0] = f2bf(xv[2 + i].x); hi[i * 4 + 1] = f2bf(xv[2 + i].y);
    hi[i * 4 + 2] = f2bf(xv[2 + i].z); hi[i * 4 + 3] = f2bf(xv[2 + i].w);
  }
  *(ushort8v*)(x_bf + (size_t)token * D_ + d0) = lo;
  *(ushort8v*)(x_bf + (size_t)token * D_ + d0 + 8) = hi;

  float s[H_];
#pragma unroll
  for (int h = 0; h < H_; ++h) {
    const float* gw = gate_w + h * D_ + d0;
    float a = 0.f;
#pragma unroll
    for (int i = 0; i < 4; ++i) {
      float4 w = *(const float4*)(gw + i * 4);
      a += xv[i].x * w.x + xv[i].y * w.y + xv[i].z * w.z + xv[i].w * w.w;
    }
    s[h] = a;
  }
#pragma unroll
  for (int h = 0; h < H_; ++h) {
#pragma unroll
    for (int off = 32; off > 0; off >>= 1) s[h] += __shfl_xor(s[h], off);
    s[h] += gate_b[h];
  }
  float m = s[0];
#pragma unroll
  for (int h = 1; h < H_; ++h) m = fmaxf(m, s[h]);
  float sum = 0.f;
#pragma unroll
  for (int h = 0; h < H_; ++h) { s[h] = expf(s[h] - m); sum += s[h]; }
  const float inv = 1.0f / sum;
#pragma unroll
  for (int h = 0; h < H_; ++h) s[h] *= inv;

  if (lane == 0) {
    float4 g0 = make_float4(s[0], s[1], s[2], s[3]);
    float4 g1 = make_float4(s[4], s[5], s[6], s[7]);
    *(float4*)(g_out + (size_t)token * H_)     = g0;
    *(float4*)(g_out + (size_t)token * H_ + 4) = g1;
  }
}

// ---------------------------------------------------------------------------
// Kernel 2: expert_w f32 -> bf16
// ---------------------------------------------------------------------------
__global__ __launch_bounds__(256) void convw_kernel(
    const float* __restrict__ w, u16* __restrict__ wb) {
  size_t i = ((size_t)blockIdx.x * 256 + threadIdx.x) * 8;
  float4 a = *(const float4*)(w + i);
  float4 b = *(const float4*)(w + i + 4);
  ushort8v v;
  v[0] = f2bf(a.x); v[1] = f2bf(a.y); v[2] = f2bf(a.z); v[3] = f2bf(a.w);
  v[4] = f2bf(b.x); v[5] = f2bf(b.y); v[6] = f2bf(b.z); v[7] = f2bf(b.w);
  *(ushort8v*)(wb + i) = v;
}

// ---------------------------------------------------------------------------
// Kernel 3: fused MoE GEMM == R12 (156us GEMM, MfmaUtil 37, 0 conflicts,
// FETCH 99MB, VGPR 92, no spill) with ONE structural change: the two
// compute phases per K-tile are FUSED into a single phase with ONE barrier
// per tile (was 4).  R12 decision-rule: square wave tile moved MfmaUtil
// only +1.4pt -> LDS BW not binding; residual = barrier lockstep.
// Correctness: mid-tile barriers protected nothing -- slot t%3 was made
// safe by end-of-(t-1) vmcnt(6)+barrier; prefetch writes go to slot
// (t+2)%3 (untouched until 2 barriers later); gloads into slot t%3 are
// issued at tile t+1, after ALL waves finished reading tile t (end-of-t
// barrier).  vmcnt ledger unchanged: 6 issues/tile, end-of-tile vmcnt(6)
// -> t+1 complete, t+2 in flight (vmcnt(0) for t >= NT-2).
// Tile body: {16 ds_read_b128 (kk0+kk1), 6 gload_lds, setprio(1),
// 32 MFMA (compiler emits fine lgkmcnt -> MFMAs start as frags land),
// setprio(0), vmcnt, s_barrier}.  Everything else identical: h-outer
// t=(h,k) walk, 3-deep ring, 3-bit XOR swizzle elem^=(row&7)<<3 (0
// conflicts), XCD row-panel-group mapping (FETCH 533->99MB), 4Mx2N wave
// grid (64x64/wave), per-h fold acc += g_h*(part+eb).
// ---------------------------------------------------------------------------
__global__ __launch_bounds__(512, 2) void moe_gemm_kernel(
    const u16* __restrict__ Xb, const u16* __restrict__ Wb,
    const float* __restrict__ g, const float* __restrict__ eb,
    float* __restrict__ out) {
  __shared__ __align__(16) u16 As[3][BM * BK];   // 3 x 32 KB
  __shared__ __align__(16) u16 Bs[3][BN * BK];   // 3 x 16 KB
  __shared__ float gs[H_][BM];                   // 8 KB, transposed
  __shared__ float ebs[H_][BN];                  // 4 KB

  const int tid  = threadIdx.x;
  const int wave = tid >> 6;
  const int lane = tid & 63;

  // ---- XCD-affine mapping: xcd = bx&7 owns row panels 4*(bx&7)+(bx>>6) ----
  const int bx   = blockIdx.x;                 // 256 blocks
  const int row0 = ((bx & 7) * 4 + (bx >> 6)) * BM;   // 32 row panels
  const int col0 = ((bx >> 3) & 7) * BN;               // 8 col panels

  for (int i = tid; i < H_ * BM; i += 512) {
    int h = i >> 8, r = i & 255;
    gs[h][r] = g[(size_t)(row0 + r) * H_ + h];
  }
  for (int i = tid; i < H_ * BN; i += 512) {
    int h = i >> 7, c = i & 127;
    ebs[h][c] = eb[h * O_ + col0 + c];
  }

  const int wm = wave >> 1;  // 0..3 : 64-row band
  const int wn = wave & 1;   // 0..1 : 64-col band

  // ---- staging source (inverse-swizzled global addr; LDS dest linear) ----
  const int s_row = wave * 8 + (lane >> 3);               // row in 64-group
  const int s_col = ((lane & 7) * 8) ^ (((lane >> 3) & 7) << 3);
  const u16* a_base = Xb + (size_t)(row0 + s_row) * D_ + s_col;
  const u16* b_base = Wb + (size_t)(col0 + s_row) * D_ + s_col;
  const int lds_off = (wave * 8) * BK;                    // elems, wave-uniform

  // ---- swizzled LDS read offsets (elements); read row&7 == lane&7 ----
  const int sw  = (lane & 7) << 3;
  const int aq  = lane >> 4;
  const int ce0 = (aq * 8) ^ sw;
  const int ce1 = (aq * 8 + 32) ^ sw;
  const int arow = (wm * 64 + (lane & 15)) * BK;
  const int brow = (wn * 64 + (lane & 15)) * BK;

  const f32x4 zero4 = {0.f, 0.f, 0.f, 0.f};
  f32x4 acc[4][4], part[4][4];
#pragma unroll
  for (int i = 0; i < 4; ++i)
#pragma unroll
    for (int j = 0; j < 4; ++j) { acc[i][j] = zero4; part[i][j] = zero4; }

  // ---- prologue: stage tiles 0 and 1 (both h=0) ----
#pragma unroll
  for (int i = 0; i < 4; ++i)
    GLOAD16(a_base + (size_t)(i * 64) * D_, &As[0][lds_off + i * 64 * BK]);
#pragma unroll
  for (int j = 0; j < 2; ++j)
    GLOAD16(b_base + (size_t)(j * 64) * D_, &Bs[0][lds_off + j * 64 * BK]);
#pragma unroll
  for (int i = 0; i < 4; ++i)
    GLOAD16(a_base + (size_t)(i * 64) * D_ + 64, &As[1][lds_off + i * 64 * BK]);
#pragma unroll
  for (int j = 0; j < 2; ++j)
    GLOAD16(b_base + (size_t)(j * 64) * D_ + 64, &Bs[1][lds_off + j * 64 * BK]);

  asm volatile("s_waitcnt vmcnt(6) lgkmcnt(0)" ::: "memory");
  __builtin_amdgcn_s_barrier();

  int buf = 0;
  for (int t = 0; t < NT; ++t) {
    const u16* Ab = &As[buf][0];
    const u16* Bb = &Bs[buf][0];
    const int t2 = t + 2;
    const int sbuf = (buf + 2 >= 3) ? buf - 1 : buf + 2;

    // ---- fused single phase: all 16 frag reads (kk0 + kk1) ----
    short8 af0[4], bf0[4], af1[4], bf1[4];
#pragma unroll
    for (int fm = 0; fm < 4; ++fm)
      af0[fm] = *(const short8*)&Ab[arow + fm * 16 * BK + ce0];
#pragma unroll
    for (int fn = 0; fn < 4; ++fn)
      bf0[fn] = *(const short8*)&Bb[brow + fn * 16 * BK + ce0];
#pragma unroll
    for (int fm = 0; fm < 4; ++fm)
      af1[fm] = *(const short8*)&Ab[arow + fm * 16 * BK + ce1];
#pragma unroll
    for (int fn = 0; fn < 4; ++fn)
      bf1[fn] = *(const short8*)&Bb[brow + fn * 16 * BK + ce1];

    // ---- prefetch tile t+2 (A and B together; 6 issues) ----
    if (t2 < NT) {
      const size_t koff = (size_t)((t2 & 15) * 64);
#pragma unroll
      for (int i = 0; i < 4; ++i)
        GLOAD16(a_base + (size_t)(i * 64) * D_ + koff,
                &As[sbuf][lds_off + i * 64 * BK]);
      const size_t boff = ((size_t)(t2 >> 4) * O_) * D_ + koff;
#pragma unroll
      for (int j = 0; j < 2; ++j)
        GLOAD16(b_base + (size_t)(j * 64) * D_ + boff,
                &Bs[sbuf][lds_off + j * 64 * BK]);
    }

    // ---- 32 MFMA (compiler interleaves lgkmcnt waits with frag arrival) ----
    __builtin_amdgcn_s_setprio(1);
#pragma unroll
    for (int fm = 0; fm < 4; ++fm)
#pragma unroll
      for (int fn = 0; fn < 4; ++fn)
        part[fm][fn] = __builtin_amdgcn_mfma_f32_16x16x32_bf16(
            af0[fm], bf0[fn], part[fm][fn], 0, 0, 0);
#pragma unroll
    for (int fm = 0; fm < 4; ++fm)
#pragma unroll
      for (int fn = 0; fn < 4; ++fn)
        part[fm][fn] = __builtin_amdgcn_mfma_f32_16x16x32_bf16(
            af1[fm], bf1[fn], part[fm][fn], 0, 0, 0);
    __builtin_amdgcn_s_setprio(0);

    // ---- one counted-vmcnt + one barrier per tile ----
    if (t < NT - 2) {
      asm volatile("s_waitcnt vmcnt(6)" ::: "memory");  // t+1 ready, t+2 in flight
    } else {
      asm volatile("s_waitcnt vmcnt(0)" ::: "memory");
    }
    __builtin_amdgcn_s_barrier();

    // ============ fold at end of each expert h ============
    if ((t & 15) == 15) {
      const int h = t >> 4;
      float ebv[4];
#pragma unroll
      for (int fn = 0; fn < 4; ++fn)
        ebv[fn] = ebs[h][wn * 64 + fn * 16 + (lane & 15)];
#pragma unroll
      for (int fm = 0; fm < 4; ++fm) {
        const f32x4 gg =
            *(const f32x4*)&gs[h][wm * 64 + fm * 16 + (lane >> 4) * 4];
#pragma unroll
        for (int fn = 0; fn < 4; ++fn)
#pragma unroll
          for (int j = 0; j < 4; ++j) {
            acc[fm][fn][j] += gg[j] * (part[fm][fn][j] + ebv[fn]);
            part[fm][fn][j] = 0.f;
          }
      }
    }

    buf = (buf == 2) ? 0 : buf + 1;
  }

  // ---- epilogue: C/D layout col = lane&15, row = (lane>>4)*4 + j ----
  const int crow = row0 + wm * 64 + (lane >> 4) * 4;
  const int ccol = col0 + wn * 64 + (lane & 15);
#pragma unroll
  for (int fm = 0; fm < 4; ++fm)
#pragma unroll
    for (int fn = 0; fn < 4; ++fn)
#pragma unroll
      for (int j = 0; j < 4; ++j)
        out[(size_t)(crow + fm * 16 + j) * O_ + (ccol + fn * 16)] =
            acc[fm][fn][j];
}

// ---------------------------------------------------------------------------
extern "C" void kernel_launch(void* const* d_in, const int* in_sizes, int n_in,
                              void* d_out, int out_size, void* d_ws,
                              size_t ws_size, hipStream_t stream) {
  const float* x   = (const float*)d_in[0];
  const float* gw  = (const float*)d_in[1];
  const float* gb  = (const float*)d_in[2];
  const float* ew  = (const float*)d_in[3];
  const float* ebp = (const float*)d_in[4];
  float* out = (float*)d_out;

  u16*   x_bf = (u16*)d_ws;                                            // 16 MB
  u16*   w_bf = (u16*)((char*)d_ws + (size_t)BS_ * D_ * 2);            // 16 MB
  float* gbuf = (float*)((char*)d_ws + (size_t)BS_ * D_ * 2 +
                         (size_t)H_ * O_ * D_ * 2);                    // 256 KB

  gate_conv_kernel<<<BS_ / 4, 256, 0, stream>>>(x, gw, gb, x_bf, gbuf);
  convw_kernel<<<(H_ * O_ * D_) / 2048, 256, 0, stream>>>(ew, w_bf);
  moe_gemm_kernel<<<(BS_ / BM) * (O_ / BN), 512, 0, stream>>>(x_bf, w_bf, gbuf,
                                                              ebp, out);
}